// Round 1
// baseline (172.773 us; speedup 1.0000x reference)
//
#include <hip/hip_runtime.h>

// ToneStack: 3 cascaded time-varying biquads over (B=16, N=96000).
// Exact parallel solution via chunked affine scan:
//   state s in R^6, s_n = T_n s_{n-1} + u_n, T block-lower-triangular.
//   K1: per-chunk symbolic composition (sparse columns, 30 floats/chunk)
//   K2: per-row hierarchical scan over chunk maps -> chunk start states
//   K3: concrete recurrence per chunk from known start state -> output

static constexpr int B  = 16;
static constexpr int N  = 96000;
static constexpr int L  = 32;        // samples per chunk
static constexpr int C  = 3000;      // chunks per row (L*C == N)
static constexpr int NC = B * C;     // total chunks
static constexpr int G  = 60;        // groups per row
static constexpr int S  = 50;        // chunks per group (G*S == C)

#define FS_INV (1.0f / 48000.0f)

__device__ __forceinline__ float frcp(float x) { return __builtin_amdgcn_rcpf(x); }

struct Coefs {
  float b0l, b1l, b2l, a1l, a2l;
  float b0m, b1m, b2m, a1m, a2m;
  float b0h, b1h, b2h, a1h, a2h;
};

__device__ __forceinline__ Coefs make_coefs(float gl, float gm, float fcm,
                                            float qm, float gh) {
  Coefs o;
  const float K = 0.08304820237218406f;  // log2(10)/40
  {  // low shelf fc=120, Q=0.707 (cosw, alpha folded to constants)
    const float cw = 0.9998766325f;      // cos(2*pi*120/48000)
    const float al = 0.0111084287f;      // sin(w0)/(2*0.707)
    float A  = __builtin_amdgcn_exp2f(gl * K);
    float sA = __builtin_amdgcn_sqrtf(A);
    float Ap1 = A + 1.0f, Am1 = A - 1.0f;
    float t = Am1 * cw, u = 2.0f * sA * al;
    float b0 = A * (Ap1 - t + u);
    float b1 = 2.0f * A * (Am1 - Ap1 * cw);
    float b2 = A * (Ap1 - t - u);
    float a0 = Ap1 + t + u;
    float a1 = -2.0f * (Am1 + Ap1 * cw);
    float a2 = Ap1 + t - u;
    float r = frcp(a0);
    o.b0l = b0 * r; o.b1l = b1 * r; o.b2l = b2 * r; o.a1l = a1 * r; o.a2l = a2 * r;
  }
  {  // peaking, time-varying fc/Q/gain
    float fc = fminf(fmaxf(fcm, 50.0f), 8000.0f);
    float Q  = fminf(fmaxf(qm, 0.2f), 4.0f);
    float rev = fc * FS_INV;                    // w0 / (2*pi): v_sin takes revolutions
    float sw  = __builtin_amdgcn_sinf(rev);
    float cwm = __builtin_amdgcn_cosf(rev);
    float A   = __builtin_amdgcn_exp2f(gm * K);
    float iA  = frcp(A);
    float alpha = sw * 0.5f * frcp(Q);
    float aA = alpha * A, aiA = alpha * iA;
    float b0 = 1.0f + aA, b1 = -2.0f * cwm, b2 = 1.0f - aA;
    float a0 = 1.0f + aiA, a2 = 1.0f - aiA;
    float r = frcp(a0);
    float b1r = b1 * r;
    o.b0m = b0 * r; o.b1m = b1r; o.b2m = b2 * r; o.a1m = b1r; o.a2m = a2 * r;
  }
  {  // high shelf fc=4000, Q=0.707
    const float cw = 0.8660254038f;      // cos(pi/6)
    const float al = 0.3536067893f;      // 0.5/1.414
    float A  = __builtin_amdgcn_exp2f(gh * K);
    float sA = __builtin_amdgcn_sqrtf(A);
    float Ap1 = A + 1.0f, Am1 = A - 1.0f;
    float t = Am1 * cw, u = 2.0f * sA * al;
    float b0 = A * (Ap1 + t + u);
    float b1 = -2.0f * A * (Am1 + Ap1 * cw);
    float b2 = A * (Ap1 + t - u);
    float a0 = Ap1 - t + u;
    float a1 = 2.0f * (Am1 - Ap1 * cw);
    float a2 = Ap1 - t - u;
    float r = frcp(a0);
    o.b0h = b0 * r; o.b1h = b1 * r; o.b2h = b2 * r; o.a1h = a1 * r; o.a2h = a2 * r;
  }
  return o;
}

// --- per-sample state steppers -------------------------------------------
// full 6-component column with input xc; returns output yh
__device__ __forceinline__ float stepF(float v[6], float xc, const Coefs& k) {
  float yl = fmaf(k.b0l, xc, v[0]);
  float n0 = fmaf(k.b1l, xc, fmaf(-k.a1l, yl, v[1]));
  float n1 = fmaf(k.b2l, xc, -k.a2l * yl);
  float ym = fmaf(k.b0m, yl, v[2]);
  float n2 = fmaf(k.b1m, yl, fmaf(-k.a1m, ym, v[3]));
  float n3 = fmaf(k.b2m, yl, -k.a2m * ym);
  float yh = fmaf(k.b0h, ym, v[4]);
  float n4 = fmaf(k.b1h, ym, fmaf(-k.a1h, yh, v[5]));
  float n5 = fmaf(k.b2h, ym, -k.a2h * yh);
  v[0] = n0; v[1] = n1; v[2] = n2; v[3] = n3; v[4] = n4; v[5] = n5;
  return yh;
}
// full basis column (xc == 0)
__device__ __forceinline__ void stepF0(float v[6], const Coefs& k) {
  float yl = v[0];
  float n0 = fmaf(-k.a1l, yl, v[1]);
  float n1 = -k.a2l * yl;
  float ym = fmaf(k.b0m, yl, v[2]);
  float n2 = fmaf(k.b1m, yl, fmaf(-k.a1m, ym, v[3]));
  float n3 = fmaf(k.b2m, yl, -k.a2m * ym);
  float yh = fmaf(k.b0h, ym, v[4]);
  float n4 = fmaf(k.b1h, ym, fmaf(-k.a1h, yh, v[5]));
  float n5 = fmaf(k.b2h, ym, -k.a2h * yh);
  v[0] = n0; v[1] = n1; v[2] = n2; v[3] = n3; v[4] = n4; v[5] = n5;
}
// mid-basis column: comps (z1m,z2m,z1h,z2h)
__device__ __forceinline__ void stepM(float v[4], const Coefs& k) {
  float ym = v[0];
  float n0 = fmaf(-k.a1m, ym, v[1]);
  float n1 = -k.a2m * ym;
  float yh = fmaf(k.b0h, ym, v[2]);
  float n2 = fmaf(k.b1h, ym, fmaf(-k.a1h, yh, v[3]));
  float n3 = fmaf(k.b2h, ym, -k.a2h * yh);
  v[0] = n0; v[1] = n1; v[2] = n2; v[3] = n3;
}
// high-basis column: comps (z1h,z2h)
__device__ __forceinline__ void stepH(float v[2], const Coefs& k) {
  float yh = v[0];
  float n0 = fmaf(-k.a1h, yh, v[1]);
  float n1 = -k.a2h * yh;
  v[0] = n0; v[1] = n1;
}

// --- affine map container (block-lower-triangular, 30 floats) -------------
struct Aff {
  float c0[6], c1[6];  // columns for z1l, z2l basis (full)
  float c2[4], c3[4];  // columns for z1m, z2m basis (rows 2..5)
  float c4[2], c5[2];  // columns for z1h, z2h basis (rows 4..5)
  float d[6];          // offset
};

__device__ __forceinline__ void loadAff(const float* __restrict__ p, Aff& a) {
  const float4* q = reinterpret_cast<const float4*>(p);
  float4 f0 = q[0], f1 = q[1], f2 = q[2], f3 = q[3];
  float4 f4 = q[4], f5 = q[5], f6 = q[6], f7 = q[7];
  a.c0[0] = f0.x; a.c0[1] = f0.y; a.c0[2] = f0.z; a.c0[3] = f0.w;
  a.c0[4] = f1.x; a.c0[5] = f1.y;
  a.c1[0] = f1.z; a.c1[1] = f1.w; a.c1[2] = f2.x; a.c1[3] = f2.y;
  a.c1[4] = f2.z; a.c1[5] = f2.w;
  a.c2[0] = f3.x; a.c2[1] = f3.y; a.c2[2] = f3.z; a.c2[3] = f3.w;
  a.c3[0] = f4.x; a.c3[1] = f4.y; a.c3[2] = f4.z; a.c3[3] = f4.w;
  a.c4[0] = f5.x; a.c4[1] = f5.y; a.c5[0] = f5.z; a.c5[1] = f5.w;
  a.d[0] = f6.x; a.d[1] = f6.y; a.d[2] = f6.z; a.d[3] = f6.w;
  a.d[4] = f7.x; a.d[5] = f7.y;
}

// r = M * v   (v, r full 6-vectors; M sparse block-lower-triangular)
__device__ __forceinline__ void applyM6(const Aff& A, const float v[6], float r[6]) {
  r[0] = v[0]*A.c0[0] + v[1]*A.c1[0];
  r[1] = v[0]*A.c0[1] + v[1]*A.c1[1];
  r[2] = v[0]*A.c0[2] + v[1]*A.c1[2] + v[2]*A.c2[0] + v[3]*A.c3[0];
  r[3] = v[0]*A.c0[3] + v[1]*A.c1[3] + v[2]*A.c2[1] + v[3]*A.c3[1];
  r[4] = v[0]*A.c0[4] + v[1]*A.c1[4] + v[2]*A.c2[2] + v[3]*A.c3[2]
       + v[4]*A.c4[0] + v[5]*A.c5[0];
  r[5] = v[0]*A.c0[5] + v[1]*A.c1[5] + v[2]*A.c2[3] + v[3]*A.c3[3]
       + v[4]*A.c4[1] + v[5]*A.c5[1];
}

// R = Mc o acc  (apply acc first, then Mc)
__device__ __forceinline__ void composeInto(const Aff& Mc, const Aff& acc, Aff& R) {
  applyM6(Mc, acc.c0, R.c0);
  applyM6(Mc, acc.c1, R.c1);
  {
    const float* a = acc.c2; float* r = R.c2;
    r[0] = a[0]*Mc.c2[0] + a[1]*Mc.c3[0];
    r[1] = a[0]*Mc.c2[1] + a[1]*Mc.c3[1];
    r[2] = a[0]*Mc.c2[2] + a[1]*Mc.c3[2] + a[2]*Mc.c4[0] + a[3]*Mc.c5[0];
    r[3] = a[0]*Mc.c2[3] + a[1]*Mc.c3[3] + a[2]*Mc.c4[1] + a[3]*Mc.c5[1];
  }
  {
    const float* a = acc.c3; float* r = R.c3;
    r[0] = a[0]*Mc.c2[0] + a[1]*Mc.c3[0];
    r[1] = a[0]*Mc.c2[1] + a[1]*Mc.c3[1];
    r[2] = a[0]*Mc.c2[2] + a[1]*Mc.c3[2] + a[2]*Mc.c4[0] + a[3]*Mc.c5[0];
    r[3] = a[0]*Mc.c2[3] + a[1]*Mc.c3[3] + a[2]*Mc.c4[1] + a[3]*Mc.c5[1];
  }
  {
    const float* a = acc.c4; float* r = R.c4;
    r[0] = a[0]*Mc.c4[0] + a[1]*Mc.c5[0];
    r[1] = a[0]*Mc.c4[1] + a[1]*Mc.c5[1];
  }
  {
    const float* a = acc.c5; float* r = R.c5;
    r[0] = a[0]*Mc.c4[0] + a[1]*Mc.c5[0];
    r[1] = a[0]*Mc.c4[1] + a[1]*Mc.c5[1];
  }
  float t[6];
  applyM6(Mc, acc.d, t);
  #pragma unroll
  for (int i = 0; i < 6; ++i) R.d[i] = t[i] + Mc.d[i];
}

__device__ __forceinline__ void setIdentity(Aff& a) {
  #pragma unroll
  for (int i = 0; i < 6; ++i) { a.c0[i] = 0.f; a.c1[i] = 0.f; a.d[i] = 0.f; }
  #pragma unroll
  for (int i = 0; i < 4; ++i) { a.c2[i] = 0.f; a.c3[i] = 0.f; }
  a.c4[0] = 0.f; a.c4[1] = 0.f; a.c5[0] = 0.f; a.c5[1] = 0.f;
  a.c0[0] = 1.f; a.c1[1] = 1.f; a.c2[0] = 1.f; a.c3[1] = 1.f;
  a.c4[0] = 1.f; a.c5[1] = 1.f;
}

// ======================= K1: per-chunk composition ========================
__global__ __launch_bounds__(256) void k_phaseA(
    const float* __restrict__ x,  const float* __restrict__ lg,
    const float* __restrict__ mg, const float* __restrict__ fc,
    const float* __restrict__ qq, const float* __restrict__ hg,
    float* __restrict__ comp) {
  int id = blockIdx.x * blockDim.x + threadIdx.x;
  if (id >= NC) return;
  int b = id / C, c = id % C;
  const int base = b * N + c * L;

  float c0[6] = {1.f, 0.f, 0.f, 0.f, 0.f, 0.f};
  float c1[6] = {0.f, 1.f, 0.f, 0.f, 0.f, 0.f};
  float c2[4] = {1.f, 0.f, 0.f, 0.f};
  float c3[4] = {0.f, 1.f, 0.f, 0.f};
  float c4[2] = {1.f, 0.f};
  float c5[2] = {0.f, 1.f};
  float dd[6] = {0.f, 0.f, 0.f, 0.f, 0.f, 0.f};

  #pragma unroll 2
  for (int i = 0; i < L; i += 4) {
    float4 xv = *reinterpret_cast<const float4*>(x  + base + i);
    float4 lv = *reinterpret_cast<const float4*>(lg + base + i);
    float4 mv = *reinterpret_cast<const float4*>(mg + base + i);
    float4 fv = *reinterpret_cast<const float4*>(fc + base + i);
    float4 qv = *reinterpret_cast<const float4*>(qq + base + i);
    float4 hv = *reinterpret_cast<const float4*>(hg + base + i);
    const float* xp = &xv.x; const float* lp = &lv.x; const float* mp = &mv.x;
    const float* fp = &fv.x; const float* qp = &qv.x; const float* hp = &hv.x;
    #pragma unroll
    for (int j = 0; j < 4; ++j) {
      Coefs k = make_coefs(lp[j], mp[j], fp[j], qp[j], hp[j]);
      stepF0(c0, k);
      stepF0(c1, k);
      stepM(c2, k);
      stepM(c3, k);
      stepH(c4, k);
      stepH(c5, k);
      stepF(dd, xp[j], k);
    }
  }
  float* o = comp + (size_t)id * 32;
  float4* ov = reinterpret_cast<float4*>(o);
  ov[0] = make_float4(c0[0], c0[1], c0[2], c0[3]);
  ov[1] = make_float4(c0[4], c0[5], c1[0], c1[1]);
  ov[2] = make_float4(c1[2], c1[3], c1[4], c1[5]);
  ov[3] = make_float4(c2[0], c2[1], c2[2], c2[3]);
  ov[4] = make_float4(c3[0], c3[1], c3[2], c3[3]);
  ov[5] = make_float4(c4[0], c4[1], c5[0], c5[1]);
  ov[6] = make_float4(dd[0], dd[1], dd[2], dd[3]);
  ov[7] = make_float4(dd[4], dd[5], 0.f, 0.f);
}

// ================= K2: per-row hierarchical scan over chunks ==============
__global__ __launch_bounds__(64) void k_phaseB(const float* __restrict__ comp,
                                               float* __restrict__ sstart) {
  __shared__ Aff  gA[G];
  __shared__ float gS[G][6];
  int b = blockIdx.x, t = threadIdx.x;

  if (t < G) {  // level 1: compose S consecutive chunk maps
    Aff acc; setIdentity(acc);
    for (int j = 0; j < S; ++j) {
      Aff Mc; loadAff(comp + (size_t)(b * C + t * S + j) * 32, Mc);
      Aff R;  composeInto(Mc, acc, R);
      acc = R;
    }
    gA[t] = acc;
  }
  __syncthreads();
  if (t == 0) {  // level 2: scan the G group maps sequentially
    float s[6] = {0.f, 0.f, 0.f, 0.f, 0.f, 0.f};
    for (int g = 0; g < G; ++g) {
      #pragma unroll
      for (int i = 0; i < 6; ++i) gS[g][i] = s[i];
      float r[6];
      applyM6(gA[g], s, r);
      #pragma unroll
      for (int i = 0; i < 6; ++i) s[i] = r[i] + gA[g].d[i];
    }
  }
  __syncthreads();
  if (t < G) {  // level 3: expand per-chunk start states within each group
    float s[6];
    #pragma unroll
    for (int i = 0; i < 6; ++i) s[i] = gS[t][i];
    for (int j = 0; j < S; ++j) {
      size_t idx = (size_t)(b * C + t * S + j);
      float* o = sstart + idx * 8;
      float4* ovp = reinterpret_cast<float4*>(o);
      ovp[0] = make_float4(s[0], s[1], s[2], s[3]);
      ovp[1] = make_float4(s[4], s[5], 0.f, 0.f);
      Aff Mc; loadAff(comp + idx * 32, Mc);
      float r[6];
      applyM6(Mc, s, r);
      #pragma unroll
      for (int i = 0; i < 6; ++i) s[i] = r[i] + Mc.d[i];
    }
  }
}

// ============== K3: concrete recurrence from known start state ============
__global__ __launch_bounds__(256) void k_phaseC(
    const float* __restrict__ x,  const float* __restrict__ lg,
    const float* __restrict__ mg, const float* __restrict__ fc,
    const float* __restrict__ qq, const float* __restrict__ hg,
    const float* __restrict__ sstart, float* __restrict__ y) {
  int id = blockIdx.x * blockDim.x + threadIdx.x;
  if (id >= NC) return;
  int b = id / C, c = id % C;
  const int base = b * N + c * L;

  const float4* sp = reinterpret_cast<const float4*>(sstart + (size_t)id * 8);
  float4 s0 = sp[0], s1 = sp[1];
  float z[6] = {s0.x, s0.y, s0.z, s0.w, s1.x, s1.y};

  #pragma unroll 2
  for (int i = 0; i < L; i += 4) {
    float4 xv = *reinterpret_cast<const float4*>(x  + base + i);
    float4 lv = *reinterpret_cast<const float4*>(lg + base + i);
    float4 mv = *reinterpret_cast<const float4*>(mg + base + i);
    float4 fv = *reinterpret_cast<const float4*>(fc + base + i);
    float4 qv = *reinterpret_cast<const float4*>(qq + base + i);
    float4 hv = *reinterpret_cast<const float4*>(hg + base + i);
    const float* xp = &xv.x; const float* lp = &lv.x; const float* mp = &mv.x;
    const float* fp = &fv.x; const float* qp = &qv.x; const float* hp = &hv.x;
    float4 outv;
    float* op = &outv.x;
    #pragma unroll
    for (int j = 0; j < 4; ++j) {
      Coefs k = make_coefs(lp[j], mp[j], fp[j], qp[j], hp[j]);
      op[j] = stepF(z, xp[j], k);
    }
    *reinterpret_cast<float4*>(y + base + i) = outv;
  }
}

// ================= fallback: plain sequential (tiny ws only) ==============
__global__ void k_naive(const float* __restrict__ x,  const float* __restrict__ lg,
                        const float* __restrict__ mg, const float* __restrict__ fc,
                        const float* __restrict__ qq, const float* __restrict__ hg,
                        float* __restrict__ y) {
  int b = threadIdx.x;
  if (b >= B) return;
  float z[6] = {0.f, 0.f, 0.f, 0.f, 0.f, 0.f};
  for (int n = 0; n < N; ++n) {
    int i = b * N + n;
    Coefs k = make_coefs(lg[i], mg[i], fc[i], qq[i], hg[i]);
    y[i] = stepF(z, x[i], k);
  }
}

extern "C" void kernel_launch(void* const* d_in, const int* in_sizes, int n_in,
                              void* d_out, int out_size, void* d_ws, size_t ws_size,
                              hipStream_t stream) {
  const float* x  = (const float*)d_in[0];
  const float* lg = (const float*)d_in[1];
  const float* mg = (const float*)d_in[2];
  const float* fc = (const float*)d_in[3];
  const float* qq = (const float*)d_in[4];
  const float* hg = (const float*)d_in[5];
  float* y = (float*)d_out;

  size_t need = (size_t)NC * 32 * sizeof(float) + (size_t)NC * 8 * sizeof(float);
  if (ws_size < need) {
    k_naive<<<1, 64, 0, stream>>>(x, lg, mg, fc, qq, hg, y);
    return;
  }
  float* comp   = (float*)d_ws;
  float* sstart = comp + (size_t)NC * 32;

  int blocks = (NC + 255) / 256;
  k_phaseA<<<blocks, 256, 0, stream>>>(x, lg, mg, fc, qq, hg, comp);
  k_phaseB<<<B, 64, 0, stream>>>(comp, sstart);
  k_phaseC<<<blocks, 256, 0, stream>>>(x, lg, mg, fc, qq, hg, sstart, y);
}

// Round 2
// 120.734 us; speedup vs baseline: 1.4310x; 1.4310x over previous
//
#include <hip/hip_runtime.h>

// ToneStack: 3 cascaded time-varying biquads over (B=16, N=96000).
// Chunked affine scan, wave-parallel:
//   K1 (A): per-chunk symbolic map (L=12 samples) + in-wave inclusive scan
//           over each 64-chunk group -> prefix maps + group totals
//   K2 (B): per-row scan of 125 group totals -> group start states
//   K3 (C): chunk start = prefix(chunk-1) applied to group start; concrete run

static constexpr int B   = 16;
static constexpr int N   = 96000;
static constexpr int L   = 12;        // samples per chunk (3 x float4)
static constexpr int C   = 8000;      // chunks per row (L*C == N)
static constexpr int NC  = B * C;     // 128000 total chunks
static constexpr int GP  = 125;       // groups per row (64 chunks each)
static constexpr int BGP = B * GP;    // 2000 group slots

#define FS_INV (1.0f / 48000.0f)

__device__ __forceinline__ float frcp(float x) { return __builtin_amdgcn_rcpf(x); }

struct Coefs {
  float b0l, b1l, b2l, a1l, a2l;
  float b0m, b1m, b2m, a1m, a2m;
  float b0h, b1h, b2h, a1h, a2h;
};

__device__ __forceinline__ Coefs make_coefs(float gl, float gm, float fcm,
                                            float qm, float gh) {
  Coefs o;
  const float K = 0.08304820237218406f;  // log2(10)/40
  {  // low shelf fc=120, Q=0.707
    const float cw = 0.9998766325f;
    const float al = 0.0111084287f;
    float A  = __builtin_amdgcn_exp2f(gl * K);
    float sA = __builtin_amdgcn_sqrtf(A);
    float Ap1 = A + 1.0f, Am1 = A - 1.0f;
    float t = Am1 * cw, u = 2.0f * sA * al;
    float b0 = A * (Ap1 - t + u);
    float b1 = 2.0f * A * (Am1 - Ap1 * cw);
    float b2 = A * (Ap1 - t - u);
    float a0 = Ap1 + t + u;
    float a1 = -2.0f * (Am1 + Ap1 * cw);
    float a2 = Ap1 + t - u;
    float r = frcp(a0);
    o.b0l = b0 * r; o.b1l = b1 * r; o.b2l = b2 * r; o.a1l = a1 * r; o.a2l = a2 * r;
  }
  {  // peaking, time-varying fc/Q/gain
    float fc = fminf(fmaxf(fcm, 50.0f), 8000.0f);
    float Q  = fminf(fmaxf(qm, 0.2f), 4.0f);
    float rev = fc * FS_INV;                    // v_sin/v_cos take revolutions
    float sw  = __builtin_amdgcn_sinf(rev);
    float cwm = __builtin_amdgcn_cosf(rev);
    float A   = __builtin_amdgcn_exp2f(gm * K);
    float iA  = frcp(A);
    float alpha = sw * 0.5f * frcp(Q);
    float aA = alpha * A, aiA = alpha * iA;
    float b0 = 1.0f + aA, b1 = -2.0f * cwm, b2 = 1.0f - aA;
    float a0 = 1.0f + aiA, a2 = 1.0f - aiA;
    float r = frcp(a0);
    float b1r = b1 * r;
    o.b0m = b0 * r; o.b1m = b1r; o.b2m = b2 * r; o.a1m = b1r; o.a2m = a2 * r;
  }
  {  // high shelf fc=4000, Q=0.707
    const float cw = 0.8660254038f;
    const float al = 0.3536067893f;
    float A  = __builtin_amdgcn_exp2f(gh * K);
    float sA = __builtin_amdgcn_sqrtf(A);
    float Ap1 = A + 1.0f, Am1 = A - 1.0f;
    float t = Am1 * cw, u = 2.0f * sA * al;
    float b0 = A * (Ap1 + t + u);
    float b1 = -2.0f * A * (Am1 + Ap1 * cw);
    float b2 = A * (Ap1 + t - u);
    float a0 = Ap1 - t + u;
    float a1 = 2.0f * (Am1 - Ap1 * cw);
    float a2 = Ap1 - t - u;
    float r = frcp(a0);
    o.b0h = b0 * r; o.b1h = b1 * r; o.b2h = b2 * r; o.a1h = a1 * r; o.a2h = a2 * r;
  }
  return o;
}

// --- per-sample state steppers -------------------------------------------
__device__ __forceinline__ float stepF(float v[6], float xc, const Coefs& k) {
  float yl = fmaf(k.b0l, xc, v[0]);
  float n0 = fmaf(k.b1l, xc, fmaf(-k.a1l, yl, v[1]));
  float n1 = fmaf(k.b2l, xc, -k.a2l * yl);
  float ym = fmaf(k.b0m, yl, v[2]);
  float n2 = fmaf(k.b1m, yl, fmaf(-k.a1m, ym, v[3]));
  float n3 = fmaf(k.b2m, yl, -k.a2m * ym);
  float yh = fmaf(k.b0h, ym, v[4]);
  float n4 = fmaf(k.b1h, ym, fmaf(-k.a1h, yh, v[5]));
  float n5 = fmaf(k.b2h, ym, -k.a2h * yh);
  v[0] = n0; v[1] = n1; v[2] = n2; v[3] = n3; v[4] = n4; v[5] = n5;
  return yh;
}
__device__ __forceinline__ void stepF0(float v[6], const Coefs& k) {
  float yl = v[0];
  float n0 = fmaf(-k.a1l, yl, v[1]);
  float n1 = -k.a2l * yl;
  float ym = fmaf(k.b0m, yl, v[2]);
  float n2 = fmaf(k.b1m, yl, fmaf(-k.a1m, ym, v[3]));
  float n3 = fmaf(k.b2m, yl, -k.a2m * ym);
  float yh = fmaf(k.b0h, ym, v[4]);
  float n4 = fmaf(k.b1h, ym, fmaf(-k.a1h, yh, v[5]));
  float n5 = fmaf(k.b2h, ym, -k.a2h * yh);
  v[0] = n0; v[1] = n1; v[2] = n2; v[3] = n3; v[4] = n4; v[5] = n5;
}
__device__ __forceinline__ void stepM(float v[4], const Coefs& k) {
  float ym = v[0];
  float n0 = fmaf(-k.a1m, ym, v[1]);
  float n1 = -k.a2m * ym;
  float yh = fmaf(k.b0h, ym, v[2]);
  float n2 = fmaf(k.b1h, ym, fmaf(-k.a1h, yh, v[3]));
  float n3 = fmaf(k.b2h, ym, -k.a2h * yh);
  v[0] = n0; v[1] = n1; v[2] = n2; v[3] = n3;
}
__device__ __forceinline__ void stepH(float v[2], const Coefs& k) {
  float yh = v[0];
  float n0 = fmaf(-k.a1h, yh, v[1]);
  float n1 = -k.a2h * yh;
  v[0] = n0; v[1] = n1;
}

// --- affine map container (block-lower-triangular, 30 floats) -------------
struct Aff {
  float c0[6], c1[6];  // columns for z1l, z2l basis (full)
  float c2[4], c3[4];  // columns for z1m, z2m basis (rows 2..5)
  float c4[2], c5[2];  // columns for z1h, z2h basis (rows 4..5)
  float d[6];          // offset
};

__device__ __forceinline__ void loadAff(const float* __restrict__ p, Aff& a) {
  const float4* q = reinterpret_cast<const float4*>(p);
  float4 f0 = q[0], f1 = q[1], f2 = q[2], f3 = q[3];
  float4 f4 = q[4], f5 = q[5], f6 = q[6], f7 = q[7];
  a.c0[0] = f0.x; a.c0[1] = f0.y; a.c0[2] = f0.z; a.c0[3] = f0.w;
  a.c0[4] = f1.x; a.c0[5] = f1.y;
  a.c1[0] = f1.z; a.c1[1] = f1.w; a.c1[2] = f2.x; a.c1[3] = f2.y;
  a.c1[4] = f2.z; a.c1[5] = f2.w;
  a.c2[0] = f3.x; a.c2[1] = f3.y; a.c2[2] = f3.z; a.c2[3] = f3.w;
  a.c3[0] = f4.x; a.c3[1] = f4.y; a.c3[2] = f4.z; a.c3[3] = f4.w;
  a.c4[0] = f5.x; a.c4[1] = f5.y; a.c5[0] = f5.z; a.c5[1] = f5.w;
  a.d[0] = f6.x; a.d[1] = f6.y; a.d[2] = f6.z; a.d[3] = f6.w;
  a.d[4] = f7.x; a.d[5] = f7.y;
}

__device__ __forceinline__ void storeAff(float* __restrict__ p, const Aff& a) {
  float4* q = reinterpret_cast<float4*>(p);
  q[0] = make_float4(a.c0[0], a.c0[1], a.c0[2], a.c0[3]);
  q[1] = make_float4(a.c0[4], a.c0[5], a.c1[0], a.c1[1]);
  q[2] = make_float4(a.c1[2], a.c1[3], a.c1[4], a.c1[5]);
  q[3] = make_float4(a.c2[0], a.c2[1], a.c2[2], a.c2[3]);
  q[4] = make_float4(a.c3[0], a.c3[1], a.c3[2], a.c3[3]);
  q[5] = make_float4(a.c4[0], a.c4[1], a.c5[0], a.c5[1]);
  q[6] = make_float4(a.d[0], a.d[1], a.d[2], a.d[3]);
  q[7] = make_float4(a.d[4], a.d[5], 0.f, 0.f);
}

// r = M * v
__device__ __forceinline__ void applyM6(const Aff& A, const float v[6], float r[6]) {
  r[0] = v[0]*A.c0[0] + v[1]*A.c1[0];
  r[1] = v[0]*A.c0[1] + v[1]*A.c1[1];
  r[2] = v[0]*A.c0[2] + v[1]*A.c1[2] + v[2]*A.c2[0] + v[3]*A.c3[0];
  r[3] = v[0]*A.c0[3] + v[1]*A.c1[3] + v[2]*A.c2[1] + v[3]*A.c3[1];
  r[4] = v[0]*A.c0[4] + v[1]*A.c1[4] + v[2]*A.c2[2] + v[3]*A.c3[2]
       + v[4]*A.c4[0] + v[5]*A.c5[0];
  r[5] = v[0]*A.c0[5] + v[1]*A.c1[5] + v[2]*A.c2[3] + v[3]*A.c3[3]
       + v[4]*A.c4[1] + v[5]*A.c5[1];
}
// s_out = M s + d
__device__ __forceinline__ void applyAff(const Aff& A, const float s[6], float r[6]) {
  float t[6];
  applyM6(A, s, t);
  #pragma unroll
  for (int i = 0; i < 6; ++i) r[i] = t[i] + A.d[i];
}

// R = Mc o acc  (apply acc first, then Mc)
__device__ __forceinline__ void composeInto(const Aff& Mc, const Aff& acc, Aff& R) {
  applyM6(Mc, acc.c0, R.c0);
  applyM6(Mc, acc.c1, R.c1);
  {
    const float* a = acc.c2; float* r = R.c2;
    r[0] = a[0]*Mc.c2[0] + a[1]*Mc.c3[0];
    r[1] = a[0]*Mc.c2[1] + a[1]*Mc.c3[1];
    r[2] = a[0]*Mc.c2[2] + a[1]*Mc.c3[2] + a[2]*Mc.c4[0] + a[3]*Mc.c5[0];
    r[3] = a[0]*Mc.c2[3] + a[1]*Mc.c3[3] + a[2]*Mc.c4[1] + a[3]*Mc.c5[1];
  }
  {
    const float* a = acc.c3; float* r = R.c3;
    r[0] = a[0]*Mc.c2[0] + a[1]*Mc.c3[0];
    r[1] = a[0]*Mc.c2[1] + a[1]*Mc.c3[1];
    r[2] = a[0]*Mc.c2[2] + a[1]*Mc.c3[2] + a[2]*Mc.c4[0] + a[3]*Mc.c5[0];
    r[3] = a[0]*Mc.c2[3] + a[1]*Mc.c3[3] + a[2]*Mc.c4[1] + a[3]*Mc.c5[1];
  }
  {
    const float* a = acc.c4; float* r = R.c4;
    r[0] = a[0]*Mc.c4[0] + a[1]*Mc.c5[0];
    r[1] = a[0]*Mc.c4[1] + a[1]*Mc.c5[1];
  }
  {
    const float* a = acc.c5; float* r = R.c5;
    r[0] = a[0]*Mc.c4[0] + a[1]*Mc.c5[0];
    r[1] = a[0]*Mc.c4[1] + a[1]*Mc.c5[1];
  }
  float t[6];
  applyM6(Mc, acc.d, t);
  #pragma unroll
  for (int i = 0; i < 6; ++i) R.d[i] = t[i] + Mc.d[i];
}

__device__ __forceinline__ void setIdentity(Aff& a) {
  #pragma unroll
  for (int i = 0; i < 6; ++i) { a.c0[i] = 0.f; a.c1[i] = 0.f; a.d[i] = 0.f; }
  #pragma unroll
  for (int i = 0; i < 4; ++i) { a.c2[i] = 0.f; a.c3[i] = 0.f; }
  a.c4[0] = 0.f; a.c4[1] = 0.f; a.c5[0] = 0.f; a.c5[1] = 0.f;
  a.c0[0] = 1.f; a.c1[1] = 1.f; a.c2[0] = 1.f; a.c3[1] = 1.f;
  a.c4[0] = 1.f; a.c5[1] = 1.f;
}

__device__ __forceinline__ Aff shflUpAff(const Aff& a, int d) {
  Aff r;
  #pragma unroll
  for (int i = 0; i < 6; ++i) {
    r.c0[i] = __shfl_up(a.c0[i], d);
    r.c1[i] = __shfl_up(a.c1[i], d);
    r.d[i]  = __shfl_up(a.d[i],  d);
  }
  #pragma unroll
  for (int i = 0; i < 4; ++i) {
    r.c2[i] = __shfl_up(a.c2[i], d);
    r.c3[i] = __shfl_up(a.c3[i], d);
  }
  r.c4[0] = __shfl_up(a.c4[0], d); r.c4[1] = __shfl_up(a.c4[1], d);
  r.c5[0] = __shfl_up(a.c5[0], d); r.c5[1] = __shfl_up(a.c5[1], d);
  return r;
}

// ========== K1: chunk map + in-wave scan (64 chunks == 1 group/wave) ======
__global__ __launch_bounds__(256) void k_phaseA(
    const float* __restrict__ x,  const float* __restrict__ lg,
    const float* __restrict__ mg, const float* __restrict__ fc,
    const float* __restrict__ qq, const float* __restrict__ hg,
    float* __restrict__ comp, float* __restrict__ gtot) {
  int id = blockIdx.x * 256 + threadIdx.x;        // exact fit: 500*256 == NC
  int lane = threadIdx.x & 63;
  int b = id / C, c = id % C;
  const int base = b * N + c * L;

  float c0[6] = {1.f, 0.f, 0.f, 0.f, 0.f, 0.f};
  float c1[6] = {0.f, 1.f, 0.f, 0.f, 0.f, 0.f};
  float c2[4] = {1.f, 0.f, 0.f, 0.f};
  float c3[4] = {0.f, 1.f, 0.f, 0.f};
  float c4[2] = {1.f, 0.f};
  float c5[2] = {0.f, 1.f};
  float dd[6] = {0.f, 0.f, 0.f, 0.f, 0.f, 0.f};

  #pragma unroll
  for (int i = 0; i < L; i += 4) {
    float4 xv = *reinterpret_cast<const float4*>(x  + base + i);
    float4 lv = *reinterpret_cast<const float4*>(lg + base + i);
    float4 mv = *reinterpret_cast<const float4*>(mg + base + i);
    float4 fv = *reinterpret_cast<const float4*>(fc + base + i);
    float4 qv = *reinterpret_cast<const float4*>(qq + base + i);
    float4 hv = *reinterpret_cast<const float4*>(hg + base + i);
    const float* xp = &xv.x; const float* lp = &lv.x; const float* mp = &mv.x;
    const float* fp = &fv.x; const float* qp = &qv.x; const float* hp = &hv.x;
    #pragma unroll
    for (int j = 0; j < 4; ++j) {
      Coefs k = make_coefs(lp[j], mp[j], fp[j], qp[j], hp[j]);
      stepF0(c0, k);
      stepF0(c1, k);
      stepM(c2, k);
      stepM(c3, k);
      stepH(c4, k);
      stepH(c5, k);
      stepF(dd, xp[j], k);
    }
  }

  Aff a;
  #pragma unroll
  for (int i = 0; i < 6; ++i) { a.c0[i] = c0[i]; a.c1[i] = c1[i]; a.d[i] = dd[i]; }
  #pragma unroll
  for (int i = 0; i < 4; ++i) { a.c2[i] = c2[i]; a.c3[i] = c3[i]; }
  a.c4[0] = c4[0]; a.c4[1] = c4[1]; a.c5[0] = c5[0]; a.c5[1] = c5[1];

  // inclusive scan over the wave (group == 64 consecutive chunks, same row)
  #pragma unroll
  for (int dlt = 1; dlt < 64; dlt <<= 1) {
    Aff o = shflUpAff(a, dlt);
    if (lane >= dlt) { Aff r; composeInto(a, o, r); a = r; }
  }

  storeAff(comp + (size_t)id * 32, a);
  if (lane == 63) {
    int g = c >> 6;
    storeAff(gtot + (size_t)(b * GP + g) * 32, a);
  }
}

// ========== K2: per-row scan of 125 group totals -> group start states ====
__global__ __launch_bounds__(64) void k_phaseB(const float* __restrict__ gtot,
                                               float* __restrict__ gstart) {
  int b = blockIdx.x, lane = threadIdx.x;
  float s[6] = {0.f, 0.f, 0.f, 0.f, 0.f, 0.f};  // state entering current round

  for (int r = 0; r < 2; ++r) {
    int g = r * 64 + lane;
    Aff a;
    if (g < GP) loadAff(gtot + (size_t)(b * GP + g) * 32, a);
    else        setIdentity(a);
    #pragma unroll
    for (int dlt = 1; dlt < 64; dlt <<= 1) {
      Aff o = shflUpAff(a, dlt);
      if (lane >= dlt) { Aff t; composeInto(a, o, t); a = t; }
    }
    float e[6];
    applyAff(a, s, e);                 // state AFTER group g
    float st[6];
    #pragma unroll
    for (int i = 0; i < 6; ++i) {
      float p = __shfl_up(e[i], 1);
      st[i] = (lane == 0) ? s[i] : p;  // state BEFORE group g
    }
    if (g < GP) {
      float* o = gstart + (size_t)(b * GP + g) * 8;
      float4* ov = reinterpret_cast<float4*>(o);
      ov[0] = make_float4(st[0], st[1], st[2], st[3]);
      ov[1] = make_float4(st[4], st[5], 0.f, 0.f);
    }
    #pragma unroll
    for (int i = 0; i < 6; ++i) s[i] = __shfl(e[i], 63);  // carry
  }
}

// ========== K3: concrete recurrence from prefix-derived start state =======
__global__ __launch_bounds__(256) void k_phaseC(
    const float* __restrict__ x,  const float* __restrict__ lg,
    const float* __restrict__ mg, const float* __restrict__ fc,
    const float* __restrict__ qq, const float* __restrict__ hg,
    const float* __restrict__ comp, const float* __restrict__ gstart,
    float* __restrict__ y) {
  int id = blockIdx.x * 256 + threadIdx.x;
  int b = id / C, c = id % C;
  int p = c & 63, g = c >> 6;
  const int base = b * N + c * L;

  const float4* gs = reinterpret_cast<const float4*>(gstart + (size_t)(b * GP + g) * 8);
  float4 g0 = gs[0], g1 = gs[1];
  float sg[6] = {g0.x, g0.y, g0.z, g0.w, g1.x, g1.y};

  float z[6];
  if (p == 0) {
    #pragma unroll
    for (int i = 0; i < 6; ++i) z[i] = sg[i];
  } else {
    Aff P;
    loadAff(comp + (size_t)(id - 1) * 32, P);   // inclusive prefix of chunk-1
    applyAff(P, sg, z);
  }

  #pragma unroll
  for (int i = 0; i < L; i += 4) {
    float4 xv = *reinterpret_cast<const float4*>(x  + base + i);
    float4 lv = *reinterpret_cast<const float4*>(lg + base + i);
    float4 mv = *reinterpret_cast<const float4*>(mg + base + i);
    float4 fv = *reinterpret_cast<const float4*>(fc + base + i);
    float4 qv = *reinterpret_cast<const float4*>(qq + base + i);
    float4 hv = *reinterpret_cast<const float4*>(hg + base + i);
    const float* xp = &xv.x; const float* lp = &lv.x; const float* mp = &mv.x;
    const float* fp = &fv.x; const float* qp = &qv.x; const float* hp = &hv.x;
    float4 outv;
    float* op = &outv.x;
    #pragma unroll
    for (int j = 0; j < 4; ++j) {
      Coefs k = make_coefs(lp[j], mp[j], fp[j], qp[j], hp[j]);
      op[j] = stepF(z, xp[j], k);
    }
    *reinterpret_cast<float4*>(y + base + i) = outv;
  }
}

// ================= fallback: plain sequential (tiny ws only) ==============
__global__ void k_naive(const float* __restrict__ x,  const float* __restrict__ lg,
                        const float* __restrict__ mg, const float* __restrict__ fc,
                        const float* __restrict__ qq, const float* __restrict__ hg,
                        float* __restrict__ y) {
  int b = threadIdx.x;
  if (b >= B) return;
  float z[6] = {0.f, 0.f, 0.f, 0.f, 0.f, 0.f};
  for (int n = 0; n < N; ++n) {
    int i = b * N + n;
    Coefs k = make_coefs(lg[i], mg[i], fc[i], qq[i], hg[i]);
    y[i] = stepF(z, x[i], k);
  }
}

extern "C" void kernel_launch(void* const* d_in, const int* in_sizes, int n_in,
                              void* d_out, int out_size, void* d_ws, size_t ws_size,
                              hipStream_t stream) {
  const float* x  = (const float*)d_in[0];
  const float* lg = (const float*)d_in[1];
  const float* mg = (const float*)d_in[2];
  const float* fc = (const float*)d_in[3];
  const float* qq = (const float*)d_in[4];
  const float* hg = (const float*)d_in[5];
  float* y = (float*)d_out;

  size_t need = ((size_t)NC * 32 + (size_t)BGP * 32 + (size_t)BGP * 8) * sizeof(float);
  if (ws_size < need) {
    k_naive<<<1, 64, 0, stream>>>(x, lg, mg, fc, qq, hg, y);
    return;
  }
  float* comp   = (float*)d_ws;
  float* gtot   = comp + (size_t)NC * 32;
  float* gstart = gtot + (size_t)BGP * 32;

  k_phaseA<<<NC / 256, 256, 0, stream>>>(x, lg, mg, fc, qq, hg, comp, gtot);
  k_phaseB<<<B, 64, 0, stream>>>(gtot, gstart);
  k_phaseC<<<NC / 256, 256, 0, stream>>>(x, lg, mg, fc, qq, hg, comp, gstart, y);
}